// Round 6
// baseline (345.078 us; speedup 1.0000x reference)
//
#include <hip/hip_runtime.h>
#include <hip/hip_bf16.h>
#include <cmath>
#include <complex>

// Problem constants
constexpr int TT  = 50;            // time length
constexpr int NB  = 50;            // batch
constexpr int NC  = 4096;          // channels
constexpr int NCH = NB * NC;       // 204800 independent series
constexpr int PAD = 49;
constexpr int EXT = TT + 2 * PAD;  // 148
constexpr int TH  = 25;            // t-half per thread (S=2 split)

struct Coefs {
    double b0[2][2], b1[2][2], b2[2][2], a1[2][2], a2[2][2];
    double zi0[2][2], zi1[2][2];
};

// ---------------- Setup kernel: build the 50x50 filtfilt+demean matrix per band ----
__global__ void __launch_bounds__(64, 1) build_M(float* __restrict__ Mt, Coefs cf) {
    __shared__ float ylds[EXT][TT];
    const int band = blockIdx.x;
    const int j = threadIdx.x;
    if (j >= TT) return;

    const double b00 = cf.b0[band][0], b10 = cf.b1[band][0], b20 = cf.b2[band][0];
    const double a10 = cf.a1[band][0], a20 = cf.a2[band][0];
    const double b01 = cf.b0[band][1], b11 = cf.b1[band][1], b21 = cf.b2[band][1];
    const double a11 = cf.a1[band][1], a21 = cf.a2[band][1];

    const double x0 = 2.0 * (j == 0 ? 1.0 : 0.0) - (j == PAD ? 1.0 : 0.0);

    double s00 = cf.zi0[band][0] * x0, s01 = cf.zi1[band][0] * x0;
    double s10 = cf.zi0[band][1] * x0, s11 = cf.zi1[band][1] * x0;
    double ylast = 0.0;
#pragma unroll
    for (int i = 0; i < EXT; ++i) {
        double xt;
        if (i < PAD)            xt = 2.0 * (j == 0 ? 1.0 : 0.0) - (j == PAD - i ? 1.0 : 0.0);
        else if (i < PAD + TT)  xt = (j == i - PAD) ? 1.0 : 0.0;
        else                    xt = 2.0 * (j == TT - 1 ? 1.0 : 0.0)
                                     - (j == 2 * TT - 2 - (i - PAD) ? 1.0 : 0.0);
        const double y0 = b00 * xt + s00;
        s00 = b10 * xt + s01 - a10 * y0;
        s01 = b20 * xt - a20 * y0;
        const double y1 = b01 * y0 + s10;
        s10 = b11 * y0 + s11 - a11 * y1;
        s11 = b21 * y0 - a21 * y1;
        ylds[i][j] = (float)y1;
        if (i == EXT - 1) ylast = y1;
    }

    s00 = cf.zi0[band][0] * ylast; s01 = cf.zi1[band][0] * ylast;
    s10 = cf.zi0[band][1] * ylast; s11 = cf.zi1[band][1] * ylast;
    float o[TT];
#pragma unroll
    for (int m = 0; m < EXT; ++m) {
        const int i = EXT - 1 - m;
        const double xt = (double)ylds[i][j];
        const double y0 = b00 * xt + s00;
        s00 = b10 * xt + s01 - a10 * y0;
        s01 = b20 * xt - a20 * y0;
        const double y1 = b01 * y0 + s10;
        s10 = b11 * y0 + s11 - a11 * y1;
        s11 = b21 * y0 - a21 * y1;
        if (i >= PAD && i < PAD + TT) o[i - PAD] = (float)y1;
    }

    float mean = 0.f;
#pragma unroll
    for (int t = 0; t < TT; ++t) mean += o[t];
    mean *= (1.0f / TT);
#pragma unroll
    for (int t = 0; t < TT; ++t)
        Mt[(band * TT + j) * TT + t] = o[t] - mean;
}

// ---------------- Kernel S: per-series stats, t-split x2 ----------------------------
// Block (64 c, 2 s, 4 b) = 512 thr = 8 waves; 832 blocks -> 26 waves/CU (vs 12.5 in
// rounds 4-5 -- the latency-bound 71 us plateau). Each thread accumulates 25 t's
// (25 VGPR accums, leaving room for deep xk load pipelining under the 85-reg cap).
// s = threadIdx.y is wave-uniform (blockDim.x = 64); readfirstlane pins the M-row
// offset into an SGPR so rows stay s_load (scalar broadcast).
// Stats via raw moments: sum_t M[t][k] = 0 (demean folded into M) => mu ~ 1e-7, so
// ss = sumsq - T*mu^2 has no cancellation. Two t-halves combine through 4 KB LDS.
__global__ void __launch_bounds__(512, 6)
stats_k(const float* __restrict__ x, const float* __restrict__ Mt,
        float2* __restrict__ st) {
    const int tx = threadIdx.x;                         // c lane
    const int c  = blockIdx.x * 64 + tx;
    const int b  = blockIdx.y * 4 + threadIdx.z;
    const int tbase = __builtin_amdgcn_readfirstlane(threadIdx.y) * TH;  // SGPR
    if (b >= NB) return;                                // wave-uniform exit
    const int i = b * NC + c;

    __shared__ float red_s[2][4][64];
    __shared__ float red_q[2][4][64];

#pragma unroll 1
    for (int band = 0; band < 2; ++band) {
        const float* __restrict__ Mb = Mt + band * TT * TT + tbase;  // SGPR base
        float f[TH];
#pragma unroll
        for (int t = 0; t < TH; ++t) f[t] = 0.f;
#pragma unroll
        for (int k = 0; k < TT; ++k) {
            const float xk = x[(size_t)k * NCH + i];
#pragma unroll
            for (int t = 0; t < TH; ++t) f[t] = fmaf(Mb[k * TT + t], xk, f[t]);
        }
        float sm = 0.f, sq = 0.f;
#pragma unroll
        for (int t = 0; t < TH; ++t) { sm += f[t]; sq = fmaf(f[t], f[t], sq); }
        red_s[threadIdx.y][threadIdx.z][tx] = sm;
        red_q[threadIdx.y][threadIdx.z][tx] = sq;
        __syncthreads();
        if (threadIdx.y == 0) {
            const float S = sm + red_s[1][threadIdx.z][tx];
            const float Q = sq + red_q[1][threadIdx.z][tx];
            const float mu = S * (1.0f / TT);
            const float ss = Q - (float)TT * mu * mu;   // exact-mean form; mu ~ 0
            st[(size_t)(band * NB + b) * NC + c] =
                make_float2(mu, 1.0f / sqrtf(ss * (1.0f / (TT - 1))));
        }
        __syncthreads();
    }
}

// ---------------- Kernel O: recompute y (t-split x2), apply quirk normalization ----
// Same 26-waves/CU shape; no stats cooperation needed -- each thread normalizes its
// own 25 t's from the L2-resident table. QUIRK (T==B==50 broadcast collision):
// out[t,b,c] = (f[t] - st[t,c].mu) * st[t,c].inv -- table row indexed by TIME t.
__global__ void __launch_bounds__(512, 6)
out_k(const float* __restrict__ x, const float* __restrict__ Mt,
      const float2* __restrict__ st, float* __restrict__ out) {
    const int tx = threadIdx.x;
    const int c  = blockIdx.x * 64 + tx;
    const int b  = blockIdx.y * 4 + threadIdx.z;
    const int tbase = __builtin_amdgcn_readfirstlane(threadIdx.y) * TH;  // SGPR
    if (b >= NB) return;
    const int i = b * NC + c;

#pragma unroll 1
    for (int band = 0; band < 2; ++band) {
        const float* __restrict__ Mb = Mt + band * TT * TT + tbase;
        float f[TH];
#pragma unroll
        for (int t = 0; t < TH; ++t) f[t] = 0.f;
#pragma unroll
        for (int k = 0; k < TT; ++k) {
            const float xk = x[(size_t)k * NCH + i];
#pragma unroll
            for (int t = 0; t < TH; ++t) f[t] = fmaf(Mb[k * TT + t], xk, f[t]);
        }
#pragma unroll
        for (int t = 0; t < TH; ++t) {
            const int tt = tbase + t;
            const float2 s = st[(size_t)(band * TT + tt) * NC + c];  // row = TIME t
            out[(size_t)(band * TT + tt) * NCH + i] = (f[t] - s.x) * s.y;
        }
    }
}

// ---------------- Host: Butterworth bandpass SOS + zi (reference-exact, double) ----
static Coefs make_coefs() {
    Coefs cf;
    const double bands[2][2] = {{0.05, 0.15}, {0.2, 0.4}};
    const int n = 2;  // ORDER
    for (int bd = 0; bd < 2; ++bd) {
        const double fs = 2.0;
        const double w1 = bands[bd][0], w2 = bands[bd][1];
        const double warped0 = 2.0 * fs * std::tan(M_PI * w1 / fs);
        const double warped1 = 2.0 * fs * std::tan(M_PI * w2 / fs);
        const double bw = warped1 - warped0;
        const double wo = std::sqrt(warped0 * warped1);
        std::complex<double> p_bp[4];
        for (int k = 1; k <= n; ++k) {
            std::complex<double> p = -std::exp(std::complex<double>(0.0, M_PI * (2 * k - 1) / (2.0 * n)));
            std::complex<double> plp = p * (bw / 2.0);
            std::complex<double> disc = std::sqrt(plp * plp - std::complex<double>(wo * wo, 0.0));
            p_bp[k - 1] = plp + disc;
            p_bp[n + k - 1] = plp - disc;
        }
        const double fs2 = 2.0 * fs;
        std::complex<double> prod(1.0, 0.0);
        for (int i = 0; i < 2 * n; ++i) prod *= (fs2 - p_bp[i]);
        const double gain = std::pow(bw, n) * std::pow(fs2, n) / prod.real();
        std::complex<double> p_d[4];
        for (int i = 0; i < 2 * n; ++i) p_d[i] = (fs2 + p_bp[i]) / (fs2 - p_bp[i]);
        double sos[2][6];
        int cnt = 0;
        for (int i = 0; i < 2 * n; ++i) {
            if (p_d[i].imag() > 0) {
                const double g = (cnt == 0) ? gain : 1.0;
                sos[cnt][0] = g;
                sos[cnt][1] = 0.0;
                sos[cnt][2] = -g;
                sos[cnt][3] = 1.0;
                sos[cnt][4] = -2.0 * p_d[i].real();
                sos[cnt][5] = std::norm(p_d[i]);
                ++cnt;
            }
        }
        double scale = 1.0;
        for (int s = 0; s < 2; ++s) {
            const double b0 = sos[s][0], b1 = sos[s][1], b2 = sos[s][2];
            const double a1 = sos[s][4], a2 = sos[s][5];
            const double B0 = b1 - a1 * b0, B1 = b2 - a2 * b0;
            const double det = 1.0 + a1 + a2;
            cf.b0[bd][s] = b0; cf.b1[bd][s] = b1; cf.b2[bd][s] = b2;
            cf.a1[bd][s] = a1; cf.a2[bd][s] = a2;
            cf.zi0[bd][s] = scale * (B0 + B1) / det;
            cf.zi1[bd][s] = scale * ((1.0 + a1) * B1 - a2 * B0) / det;
            scale *= (b0 + b1 + b2) / (1.0 + a1 + a2);
        }
    }
    return cf;
}

extern "C" void kernel_launch(void* const* d_in, const int* in_sizes, int n_in,
                              void* d_out, int out_size, void* d_ws, size_t ws_size,
                              hipStream_t stream) {
    const float* x = (const float*)d_in[0];
    float* out = (float*)d_out;
    float* Mt = (float*)d_ws;                                  // 20 KB at offset 0
    float2* st = (float2*)((char*)d_ws + 32768);               // 2*50*4096*8 = 3.3 MB

    const Coefs cf = make_coefs();
    build_M<<<dim3(2), dim3(64), 0, stream>>>(Mt, cf);

    dim3 blk(64, 2, 4);                                        // c, t-half, b-sub
    dim3 grd(NC / 64, (NB + 3) / 4);                           // 64 x 13 blocks
    stats_k<<<grd, blk, 0, stream>>>(x, Mt, st);
    out_k<<<grd, blk, 0, stream>>>(x, Mt, st, out);
}